// Round 1
// baseline (414.088 us; speedup 1.0000x reference)
//
#include <hip/hip_runtime.h>
#include <hip/hip_bf16.h>

typedef __attribute__((ext_vector_type(8))) short short8;
typedef __attribute__((ext_vector_type(4))) float floatx4;

#define MFMA16(a, b, c) __builtin_amdgcn_mfma_f32_16x16x32_bf16((a), (b), (c), 0, 0, 0)
#define GLOBAL_AS __attribute__((address_space(1)))
#define LDS_AS __attribute__((address_space(3)))

__device__ __forceinline__ unsigned short f2bf(float x) {
  union { float f; unsigned u; } v; v.f = x;
  unsigned r = v.u + 0x7FFFu + ((v.u >> 16) & 1u);  // RNE
  return (unsigned short)(r >> 16);
}

__device__ __forceinline__ short8 ld8(const unsigned short* p) {
  return *reinterpret_cast<const short8*>(p);
}

__device__ __forceinline__ void async_cp16(const unsigned short* g, unsigned short* l) {
  __builtin_amdgcn_global_load_lds((const GLOBAL_AS void*)g, (LDS_AS void*)l, 16, 0, 0);
}

// ---------------- fused prep: x convert + both weight transposes ----------------
// R18: also zeroes the 512 attn pair-counters (replaces a memset launch).
__global__ __launch_bounds__(256) void k_prep(
    const float* __restrict__ x, unsigned short* __restrict__ xb,
    const float* __restrict__ w_qkv, unsigned short* __restrict__ wqkvT,
    const float* __restrict__ w_proj, unsigned short* __restrict__ wprojT,
    int* __restrict__ counters) {
  __shared__ float tile[64][65];
  int bid = blockIdx.x, tid = threadIdx.x;
  if (bid == 0) {  // zero attn finalize counters (k_attn runs strictly after)
    counters[tid] = 0;
    counters[tid + 256] = 0;
  }
  if (bid < 4096) {
    int i = bid * 256 + tid;
    float4 f = reinterpret_cast<const float4*>(x)[i];
    union { unsigned short u[4]; unsigned long long v; } o;
    o.u[0] = f2bf(f.x); o.u[1] = f2bf(f.y); o.u[2] = f2bf(f.z); o.u[3] = f2bf(f.w);
    reinterpret_cast<unsigned long long*>(xb)[i] = o.v;
    return;
  }
  const float* in; unsigned short* out; int R, C, bx, by;
  if (bid < 4864) {
    int rel = bid - 4096;
    in = w_qkv; out = wqkvT; R = 1024; C = 3072; bx = rel % 48; by = rel / 48;
  } else {
    int rel = bid - 4864;
    in = w_proj; out = wprojT; R = 1024; C = 1024; bx = rel % 16; by = rel / 16;
  }
  int tx = tid & 63, ty = tid >> 6;
  int c0 = bx * 64, r0 = by * 64;
  for (int i = ty; i < 64; i += 4)
    tile[i][tx] = in[(size_t)(r0 + i) * C + c0 + tx];
  __syncthreads();
  for (int i = ty; i < 64; i += 4)
    out[(size_t)(c0 + i) * R + r0 + tx] = f2bf(tile[tx][i]);
}

// ---------------- QKV GEMM 128x128, BK=64, fused V-transpose epilogue ----------
// Frozen at the R12/R15 anchor.
__global__ __launch_bounds__(256) void k_gemm_qkv(
    const unsigned short* __restrict__ A, const unsigned short* __restrict__ Bt,
    unsigned short* __restrict__ qk, unsigned short* __restrict__ vT, int K) {
  __shared__ unsigned short As[128][64];
  __shared__ unsigned short Bs[128][64];
  int tid = threadIdx.x;
  int w = tid >> 6, lane = tid & 63, quad = lane >> 4, l16 = lane & 15;
  int wy = w >> 1, wx = w & 1;
  int rowB = blockIdx.y * 128, colB = blockIdx.x * 128;
  int srcRow = lane >> 3;
  int srcCol = (((lane & 7) ^ (srcRow & 7)) << 3);

  floatx4 acc[4][4];
  floatx4 zero4 = {0.f, 0.f, 0.f, 0.f};
#pragma unroll
  for (int mi = 0; mi < 4; ++mi)
#pragma unroll
    for (int ni = 0; ni < 4; ++ni) acc[mi][ni] = zero4;

  for (int kt = 0; kt < K; kt += 64) {
    __syncthreads();
#pragma unroll
    for (int i = 0; i < 4; ++i) {
      int r0 = w * 32 + i * 8;
      async_cp16(&A[(size_t)(rowB + r0 + srcRow) * K + kt + srcCol], &As[r0][0]);
      async_cp16(&Bt[(size_t)(colB + r0 + srcRow) * K + kt + srcCol], &Bs[r0][0]);
    }
    __syncthreads();
#pragma unroll
    for (int kh = 0; kh < 2; ++kh) {
      short8 af[4], bf_[4];
#pragma unroll
      for (int mi = 0; mi < 4; ++mi)
        af[mi] = ld8(&As[wy * 64 + mi * 16 + l16][((kh * 4 + quad) ^ (l16 & 7)) << 3]);
#pragma unroll
      for (int ni = 0; ni < 4; ++ni)
        bf_[ni] = ld8(&Bs[wx * 64 + ni * 16 + l16][((kh * 4 + quad) ^ (l16 & 7)) << 3]);
#pragma unroll
      for (int mi = 0; mi < 4; ++mi)
#pragma unroll
        for (int ni = 0; ni < 4; ++ni)
          acc[mi][ni] = MFMA16(af[mi], bf_[ni], acc[mi][ni]);
    }
  }

  if (colB < 2048) {  // Q/K: row-major, LD 2048
#pragma unroll
    for (int mi = 0; mi < 4; ++mi) {
      int row = rowB + wy * 64 + mi * 16 + quad * 4;
#pragma unroll
      for (int ni = 0; ni < 4; ++ni) {
        int col = colB + wx * 64 + ni * 16 + l16;
#pragma unroll
        for (int r = 0; r < 4; ++r)
          qk[(size_t)(row + r) * 2048 + col] = f2bf(acc[mi][ni][r]);
      }
    }
  } else {  // V: transposed into vT[bh][d][t], packed 4x bf16 = 8B store
#pragma unroll
    for (int mi = 0; mi < 4; ++mi) {
      int row = rowB + wy * 64 + mi * 16 + quad * 4;
      int b = row >> 11, t = row & 2047;
#pragma unroll
      for (int ni = 0; ni < 4; ++ni) {
        int hd = colB - 2048 + wx * 64 + ni * 16 + l16;  // h*64+d
        union { unsigned short u[4]; unsigned long long v; } o;
#pragma unroll
        for (int r = 0; r < 4; ++r) o.u[r] = f2bf(acc[mi][ni][r]);
        *reinterpret_cast<unsigned long long*>(
            &vT[((size_t)(b * 16) * 64 + hd) * 2048 + t]) = o.v;
      }
    }
  }
}

// ---------------- proj GEMM 128x64 tiles: 512 blocks = 2/CU -------------------
__global__ __launch_bounds__(256) void k_gemm_proj(
    const unsigned short* __restrict__ A, const unsigned short* __restrict__ Bt,
    float* __restrict__ Cout, const float* __restrict__ bias, int M, int N, int K) {
  __shared__ unsigned short As[128][64];
  __shared__ unsigned short Bs[64][64];
  int tid = threadIdx.x;
  int w = tid >> 6, lane = tid & 63, quad = lane >> 4, l16 = lane & 15;
  int rowB = blockIdx.y * 128, colB = blockIdx.x * 64;
  int srcRow = lane >> 3;
  int srcCol = (((lane & 7) ^ (srcRow & 7)) << 3);

  floatx4 acc[2][4];
  floatx4 zero4 = {0.f, 0.f, 0.f, 0.f};
#pragma unroll
  for (int mi = 0; mi < 2; ++mi)
#pragma unroll
    for (int ni = 0; ni < 4; ++ni) acc[mi][ni] = zero4;

  for (int kt = 0; kt < K; kt += 64) {
    __syncthreads();
#pragma unroll
    for (int i = 0; i < 4; ++i) {
      int r0 = w * 32 + i * 8;
      async_cp16(&A[(size_t)(rowB + r0 + srcRow) * K + kt + srcCol], &As[r0][0]);
    }
#pragma unroll
    for (int i = 0; i < 2; ++i) {
      int r0 = w * 16 + i * 8;
      async_cp16(&Bt[(size_t)(colB + r0 + srcRow) * K + kt + srcCol], &Bs[r0][0]);
    }
    __syncthreads();
#pragma unroll
    for (int kh = 0; kh < 2; ++kh) {
      short8 af[2], bf_[4];
#pragma unroll
      for (int mi = 0; mi < 2; ++mi)
        af[mi] = ld8(&As[w * 32 + mi * 16 + l16][((kh * 4 + quad) ^ (l16 & 7)) << 3]);
#pragma unroll
      for (int ni = 0; ni < 4; ++ni)
        bf_[ni] = ld8(&Bs[ni * 16 + l16][((kh * 4 + quad) ^ (l16 & 7)) << 3]);
#pragma unroll
      for (int mi = 0; mi < 2; ++mi)
#pragma unroll
        for (int ni = 0; ni < 4; ++ni)
          acc[mi][ni] = MFMA16(af[mi], bf_[ni], acc[mi][ni]);
    }
  }

#pragma unroll
  for (int mi = 0; mi < 2; ++mi) {
    int row = rowB + w * 32 + mi * 16 + quad * 4;
#pragma unroll
    for (int ni = 0; ni < 4; ++ni) {
      int col = colB + ni * 16 + l16;
      float bv = bias[col];
#pragma unroll
      for (int r = 0; r < 4; ++r)
        Cout[(size_t)(row + r) * N + col] = acc[mi][ni][r] + bv;
    }
  }
}

// ---------------- flash attention, causal, fixed-offset softmax ----------------
// R18: key-split occupancy doubling. The fixed-offset softmax (p = exp2(s*c-16),
// no running max) makes o_acc and l_acc PLAIN SUMS over keys, so the key range
// of each diagonal pair (ip, 31-ip) splits additively across 2 blocks:
//   grid 512 -> 1024 blocks, 4 blocks/CU, 16 waves/CU (was 2 blocks, 8 waves).
// Split point hsplit balances work: each half does ~16.5 of the pair's 33
// stream-half units, so per-CU balance holds by construction.
// Stages are now 64-key (Kt/Vt [64][72]) so 4 x 37.9 KB LDS fits 160 KB/CU.
// Each half writes f32 partials (o: 32KB, l: 0.5KB); the SECOND block to finish
// (device-scope counter, fence/atomic/fence) sums, divides by l, stores bf16.
// XCD-affine decode: idx&7 == bh&7, both halves of a pair on the same XCD ->
// sibling partial read is an L2 hit; per-XCD K/V set 2 MB < 4 MB L2.
// Rest frozen at R16: S^T = K*Q^T, fixed-offset softmax, l via ones-MFMA,
// RNE b64 P-pack, Pt stride 76, reg-prefetch of next K/V tile.
__global__ __launch_bounds__(256, 4) void k_attn(
    const unsigned short* __restrict__ qk, const unsigned short* __restrict__ vT,
    unsigned short* __restrict__ attn_out,
    float* __restrict__ o_part, float* __restrict__ l_part,
    int* __restrict__ counters) {
  const int T = 2048, LD = 2048;
  __shared__ unsigned short Kt[64][72];        // [key][d]   64-key stage
  __shared__ unsigned short Vt[64][72];        // [d][key]
  __shared__ unsigned short Pt[4][2][16][76];  // per-wave per-stream P [q][key64]
  __shared__ int done;

  // decode: idx = (bh&7) | (hf<<3) | (ip<<4) | ((bh>>3)<<8)
  int idx = blockIdx.x;
  int hf = (idx >> 3) & 1;                   // key-range half 0/1
  int ip = (idx >> 4) & 15;                  // pair id 0..15
  int bh = (idx & 7) | ((idx >> 8) << 3);    // 0..31
  int b = bh >> 4, h = bh & 15;
  int pid = bh * 16 + ip;                    // 0..511
  int slot = pid * 2 + hf;
  int tid = threadIdx.x, w = tid >> 6, lane = tid & 63;
  int quad = lane >> 4, l16 = lane & 15;

  const unsigned short* Qp = qk + (size_t)b * T * LD + h * 64;
  const unsigned short* Kp = Qp + 1024;
  const unsigned short* Vp = vT + (size_t)bh * 64 * T;

  const int q0s[2] = {ip * 64, (31 - ip) * 64};  // static-m indexing only
  const int last64[2] = {ip, 31 - ip};           // diagonal 64-key tile index
  int NH = 32 - ip;                              // total 64-key halves (stream1)
  int hsplit = (ip >= 8) ? 9 : 16 - ip;          // ~17/16 stream-half balance
  int h0 = hf ? hsplit : 0;
  int h1 = hf ? NH : hsplit;

  short8 aq[2][2];
#pragma unroll
  for (int m = 0; m < 2; ++m) {
    const unsigned short* qrow = Qp + (size_t)(q0s[m] + w * 16 + l16) * LD + quad * 8;
    aq[m][0] = ld8(qrow);
    aq[m][1] = ld8(qrow + 32);
  }

  short8 ones8;
  {
    unsigned short o = 0x3F80;  // bf16 1.0
#pragma unroll
    for (int j = 0; j < 8; ++j) ones8[j] = (short)o;
  }

  const float cscale = 0.125f * 1.44269504f;
  floatx4 o_acc[2][4], l_acc[2];
  floatx4 zero4 = {0.f, 0.f, 0.f, 0.f};
#pragma unroll
  for (int m = 0; m < 2; ++m) {
    l_acc[m] = zero4;
#pragma unroll
    for (int nd = 0; nd < 4; ++nd) o_acc[m][nd] = zero4;
  }

  // staging coords: K 64x64 (32 rows/pass x2), V^T 64x64 (32 rows/pass x2)
  int skR = tid >> 3, skC = (tid & 7) << 3;

  short8 kreg[2], vreg[2];
#pragma unroll
  for (int j = 0; j < 2; ++j) {
    kreg[j] = ld8(&Kp[(size_t)(h0 * 64 + skR + j * 32) * LD + skC]);
    vreg[j] = ld8(&Vp[(size_t)(skR + j * 32) * T + h0 * 64 + skC]);
  }

  for (int half = h0; half < h1; ++half) {
    __syncthreads();
#pragma unroll
    for (int j = 0; j < 2; ++j) {
      *reinterpret_cast<short8*>(&Kt[skR + j * 32][skC]) = kreg[j];
      *reinterpret_cast<short8*>(&Vt[skR + j * 32][skC]) = vreg[j];
    }
    __syncthreads();

    if (half + 1 < h1) {  // prefetch next 64-key tile during compute
      int key0n = (half + 1) * 64;
#pragma unroll
      for (int j = 0; j < 2; ++j) {
        kreg[j] = ld8(&Kp[(size_t)(key0n + skR + j * 32) * LD + skC]);
        vreg[j] = ld8(&Vp[(size_t)(skR + j * 32) * T + key0n + skC]);
      }
    }

    bool act0 = (half <= last64[0]);  // stream1 always active: half <= 31-ip
    int key0 = half * 64;

    // S^T = K Q^T; C-layout: col=q=l16, row=key=kt4*16+quad*4+reg
    floatx4 st[2][4];
#pragma unroll
    for (int kt4 = 0; kt4 < 4; ++kt4) {
      short8 ak0 = ld8(&Kt[kt4 * 16 + l16][quad * 8]);
      short8 ak1 = ld8(&Kt[kt4 * 16 + l16][32 + quad * 8]);
      st[1][kt4] = MFMA16(ak0, aq[1][0], zero4);
      st[1][kt4] = MFMA16(ak1, aq[1][1], st[1][kt4]);
      if (act0) {
        st[0][kt4] = MFMA16(ak0, aq[0][0], zero4);
        st[0][kt4] = MFMA16(ak1, aq[0][1], st[0][kt4]);
      }
    }

#pragma unroll
    for (int m = 0; m < 2; ++m) {  // STATIC unroll (no dynamic indexing!)
      if (m == 0 && !act0) continue;
      if (half == last64[m]) {  // wave-uniform: mask only on diagonal tile
        int qlane = q0s[m] + w * 16 + l16;
#pragma unroll
        for (int kt4 = 0; kt4 < 4; ++kt4)
#pragma unroll
          for (int r = 0; r < 4; ++r)
            if (key0 + kt4 * 16 + quad * 4 + r > qlane) st[m][kt4][r] = -1e30f;
      }
#pragma unroll
      for (int kt4 = 0; kt4 < 4; ++kt4) {
        unsigned u[4];
#pragma unroll
        for (int r = 0; r < 4; ++r) {
          float p = __builtin_amdgcn_exp2f(fmaf(st[m][kt4][r], cscale, -16.f));
          u[r] = __float_as_uint(p) + 0x8000u;
        }
        unsigned lo = __builtin_amdgcn_perm(u[1], u[0], 0x07060302u);
        unsigned hi = __builtin_amdgcn_perm(u[3], u[2], 0x07060302u);
        unsigned long long pv = ((unsigned long long)hi << 32) | lo;
        *reinterpret_cast<unsigned long long*>(
            &Pt[w][m][l16][kt4 * 16 + quad * 4]) = pv;
      }
    }

    short8 pa[2][2];
    pa[1][0] = ld8(&Pt[w][1][l16][quad * 8]);
    pa[1][1] = ld8(&Pt[w][1][l16][32 + quad * 8]);
    if (act0) {
      pa[0][0] = ld8(&Pt[w][0][l16][quad * 8]);
      pa[0][1] = ld8(&Pt[w][0][l16][32 + quad * 8]);
    }
#pragma unroll
    for (int nd = 0; nd < 4; ++nd) {
      short8 bv0 = ld8(&Vt[nd * 16 + l16][quad * 8]);
      short8 bv1 = ld8(&Vt[nd * 16 + l16][32 + quad * 8]);
      o_acc[1][nd] = MFMA16(pa[1][0], bv0, o_acc[1][nd]);
      o_acc[1][nd] = MFMA16(pa[1][1], bv1, o_acc[1][nd]);
      if (act0) {
        o_acc[0][nd] = MFMA16(pa[0][0], bv0, o_acc[0][nd]);
        o_acc[0][nd] = MFMA16(pa[0][1], bv1, o_acc[0][nd]);
      }
    }
    l_acc[1] = MFMA16(pa[1][0], ones8, l_acc[1]);
    l_acc[1] = MFMA16(pa[1][1], ones8, l_acc[1]);
    if (act0) {
      l_acc[0] = MFMA16(pa[0][0], ones8, l_acc[0]);
      l_acc[0] = MFMA16(pa[0][1], ones8, l_acc[0]);
    }
  }

  // ---- partial epilogue: store f32 o/l partials for this half ----
  float* OP = o_part + (size_t)slot * (2 * 64 * 64);
  float* LP = l_part + (size_t)slot * (2 * 64);
#pragma unroll
  for (int m = 0; m < 2; ++m)
#pragma unroll
    for (int nd = 0; nd < 4; ++nd)
#pragma unroll
      for (int r = 0; r < 4; ++r)
        OP[(m * 64 + w * 16 + quad * 4 + r) * 64 + nd * 16 + l16] = o_acc[m][nd][r];
  if (l16 == 0)
#pragma unroll
    for (int m = 0; m < 2; ++m)
#pragma unroll
      for (int r = 0; r < 4; ++r)
        LP[m * 64 + w * 16 + quad * 4 + r] = l_acc[m][r];

  // release own stores, then bump the pair counter (device scope)
  __threadfence();
  __syncthreads();
  if (tid == 0) done = atomicAdd(&counters[pid], 1);
  __syncthreads();
  if (done != 1) return;  // first finisher leaves; second finalizes

  __threadfence();  // acquire: invalidate before reading sibling's partials
  const float* PA = o_part + (size_t)(pid * 2) * (2 * 64 * 64);
  const float* PB = PA + 2 * 64 * 64;
  const float* LA = l_part + (size_t)(pid * 2) * (2 * 64);
  const float* LB = LA + 2 * 64;
#pragma unroll
  for (int m = 0; m < 2; ++m) {
    int qg0 = q0s[m];
#pragma unroll
    for (int pass = 0; pass < 4; ++pass) {
      int q = pass * 16 + (tid >> 4);
      int d0 = (tid & 15) * 4;
      int off = (m * 64 + q) * 64 + d0;
      float4 a = *reinterpret_cast<const float4*>(&PA[off]);
      float4 c = *reinterpret_cast<const float4*>(&PB[off]);
      float rl = 1.0f / (LA[m * 64 + q] + LB[m * 64 + q]);
      union { unsigned short u[4]; unsigned long long v; } ob;
      ob.u[0] = f2bf((a.x + c.x) * rl);
      ob.u[1] = f2bf((a.y + c.y) * rl);
      ob.u[2] = f2bf((a.z + c.z) * rl);
      ob.u[3] = f2bf((a.w + c.w) * rl);
      *reinterpret_cast<unsigned long long*>(
          &attn_out[(size_t)(b * T + qg0 + q) * 1024 + h * 64 + d0]) = ob.v;
    }
  }
}

extern "C" void kernel_launch(void* const* d_in, const int* in_sizes, int n_in,
                              void* d_out, int out_size, void* d_ws, size_t ws_size,
                              hipStream_t stream) {
  const float* x = (const float*)d_in[0];       // [2,2048,1024]
  const float* w_qkv = (const float*)d_in[1];   // [1024,3072]
  const float* w_proj = (const float*)d_in[2];  // [1024,1024]
  const float* b_proj = (const float*)d_in[3];  // [1024]
  float* out = (float*)d_out;                   // [2,2048,1024] fp32

  char* ws = (char*)d_ws;
  unsigned short* xb     = (unsigned short*)(ws);                      // 8 MB
  unsigned short* wqkvT  = (unsigned short*)(ws + (size_t)(8  << 20)); // 6 MB
  unsigned short* wprojT = (unsigned short*)(ws + (size_t)(14 << 20)); // 2 MB
  unsigned short* qkb    = (unsigned short*)(ws + (size_t)(16 << 20)); // 16 MB (Q|K, LD 2048)
  unsigned short* attnb  = (unsigned short*)(ws + (size_t)(32 << 20)); // 8 MB
  unsigned short* vTb    = (unsigned short*)(ws + (size_t)(40 << 20)); // 8 MB
  float*          o_part = (float*)(ws + (size_t)(48 << 20));          // 32 MB (1024 x 32 KB)
  float*          l_part = (float*)(ws + (size_t)(80 << 20));          // 512 KB
  int*            counters = (int*)(ws + (size_t)(80 << 20) + (512 << 10)); // 2 KB

  k_prep<<<5120, 256, 0, stream>>>(x, xb, w_qkv, wqkvT, w_proj, wprojT, counters);
  k_gemm_qkv<<<dim3(3072 / 128, 4096 / 128), 256, 0, stream>>>(
      xb, wqkvT, qkb, vTb, 1024);
  k_attn<<<1024, 256, 0, stream>>>(qkb, vTb, attnb, o_part, l_part, counters);
  k_gemm_proj<<<dim3(1024 / 64, 4096 / 128), 256, 0, stream>>>(
      attnb, wprojT, out, b_proj, 4096, 1024, 1024);
}

// Round 2
// 183.707 us; speedup vs baseline: 2.2541x; 2.2541x over previous
//
#include <hip/hip_runtime.h>
#include <hip/hip_bf16.h>

typedef __attribute__((ext_vector_type(8))) short short8;
typedef __attribute__((ext_vector_type(4))) float floatx4;

#define MFMA16(a, b, c) __builtin_amdgcn_mfma_f32_16x16x32_bf16((a), (b), (c), 0, 0, 0)
#define GLOBAL_AS __attribute__((address_space(1)))
#define LDS_AS __attribute__((address_space(3)))

__device__ __forceinline__ unsigned short f2bf(float x) {
  union { float f; unsigned u; } v; v.f = x;
  unsigned r = v.u + 0x7FFFu + ((v.u >> 16) & 1u);  // RNE
  return (unsigned short)(r >> 16);
}

__device__ __forceinline__ short8 ld8(const unsigned short* p) {
  return *reinterpret_cast<const short8*>(p);
}

__device__ __forceinline__ void async_cp16(const unsigned short* g, unsigned short* l) {
  __builtin_amdgcn_global_load_lds((const GLOBAL_AS void*)g, (LDS_AS void*)l, 16, 0, 0);
}

// ---------------- fused prep: x convert + both weight transposes ----------------
__global__ __launch_bounds__(256) void k_prep(
    const float* __restrict__ x, unsigned short* __restrict__ xb,
    const float* __restrict__ w_qkv, unsigned short* __restrict__ wqkvT,
    const float* __restrict__ w_proj, unsigned short* __restrict__ wprojT) {
  __shared__ float tile[64][65];
  int bid = blockIdx.x, tid = threadIdx.x;
  if (bid < 4096) {
    int i = bid * 256 + tid;
    float4 f = reinterpret_cast<const float4*>(x)[i];
    union { unsigned short u[4]; unsigned long long v; } o;
    o.u[0] = f2bf(f.x); o.u[1] = f2bf(f.y); o.u[2] = f2bf(f.z); o.u[3] = f2bf(f.w);
    reinterpret_cast<unsigned long long*>(xb)[i] = o.v;
    return;
  }
  const float* in; unsigned short* out; int R, C, bx, by;
  if (bid < 4864) {
    int rel = bid - 4096;
    in = w_qkv; out = wqkvT; R = 1024; C = 3072; bx = rel % 48; by = rel / 48;
  } else {
    int rel = bid - 4864;
    in = w_proj; out = wprojT; R = 1024; C = 1024; bx = rel % 16; by = rel / 16;
  }
  int tx = tid & 63, ty = tid >> 6;
  int c0 = bx * 64, r0 = by * 64;
  for (int i = ty; i < 64; i += 4)
    tile[i][tx] = in[(size_t)(r0 + i) * C + c0 + tx];
  __syncthreads();
  for (int i = ty; i < 64; i += 4)
    out[(size_t)(c0 + i) * R + r0 + tx] = f2bf(tile[tx][i]);
}

// ---------------- QKV GEMM 128x128, BK=64, fused V-transpose epilogue ----------
// Frozen at the R12/R15 anchor.
__global__ __launch_bounds__(256) void k_gemm_qkv(
    const unsigned short* __restrict__ A, const unsigned short* __restrict__ Bt,
    unsigned short* __restrict__ qk, unsigned short* __restrict__ vT, int K) {
  __shared__ unsigned short As[128][64];
  __shared__ unsigned short Bs[128][64];
  int tid = threadIdx.x;
  int w = tid >> 6, lane = tid & 63, quad = lane >> 4, l16 = lane & 15;
  int wy = w >> 1, wx = w & 1;
  int rowB = blockIdx.y * 128, colB = blockIdx.x * 128;
  int srcRow = lane >> 3;
  int srcCol = (((lane & 7) ^ (srcRow & 7)) << 3);

  floatx4 acc[4][4];
  floatx4 zero4 = {0.f, 0.f, 0.f, 0.f};
#pragma unroll
  for (int mi = 0; mi < 4; ++mi)
#pragma unroll
    for (int ni = 0; ni < 4; ++ni) acc[mi][ni] = zero4;

  for (int kt = 0; kt < K; kt += 64) {
    __syncthreads();
#pragma unroll
    for (int i = 0; i < 4; ++i) {
      int r0 = w * 32 + i * 8;
      async_cp16(&A[(size_t)(rowB + r0 + srcRow) * K + kt + srcCol], &As[r0][0]);
      async_cp16(&Bt[(size_t)(colB + r0 + srcRow) * K + kt + srcCol], &Bs[r0][0]);
    }
    __syncthreads();
#pragma unroll
    for (int kh = 0; kh < 2; ++kh) {
      short8 af[4], bf_[4];
#pragma unroll
      for (int mi = 0; mi < 4; ++mi)
        af[mi] = ld8(&As[wy * 64 + mi * 16 + l16][((kh * 4 + quad) ^ (l16 & 7)) << 3]);
#pragma unroll
      for (int ni = 0; ni < 4; ++ni)
        bf_[ni] = ld8(&Bs[wx * 64 + ni * 16 + l16][((kh * 4 + quad) ^ (l16 & 7)) << 3]);
#pragma unroll
      for (int mi = 0; mi < 4; ++mi)
#pragma unroll
        for (int ni = 0; ni < 4; ++ni)
          acc[mi][ni] = MFMA16(af[mi], bf_[ni], acc[mi][ni]);
    }
  }

  if (colB < 2048) {  // Q/K: row-major, LD 2048
#pragma unroll
    for (int mi = 0; mi < 4; ++mi) {
      int row = rowB + wy * 64 + mi * 16 + quad * 4;
#pragma unroll
      for (int ni = 0; ni < 4; ++ni) {
        int col = colB + wx * 64 + ni * 16 + l16;
#pragma unroll
        for (int r = 0; r < 4; ++r)
          qk[(size_t)(row + r) * 2048 + col] = f2bf(acc[mi][ni][r]);
      }
    }
  } else {  // V: transposed into vT[bh][d][t], packed 4x bf16 = 8B store
#pragma unroll
    for (int mi = 0; mi < 4; ++mi) {
      int row = rowB + wy * 64 + mi * 16 + quad * 4;
      int b = row >> 11, t = row & 2047;
#pragma unroll
      for (int ni = 0; ni < 4; ++ni) {
        int hd = colB - 2048 + wx * 64 + ni * 16 + l16;  // h*64+d
        union { unsigned short u[4]; unsigned long long v; } o;
#pragma unroll
        for (int r = 0; r < 4; ++r) o.u[r] = f2bf(acc[mi][ni][r]);
        *reinterpret_cast<unsigned long long*>(
            &vT[((size_t)(b * 16) * 64 + hd) * 2048 + t]) = o.v;
      }
    }
  }
}

// ---------------- proj GEMM 128x64 tiles: 512 blocks = 2/CU -------------------
__global__ __launch_bounds__(256) void k_gemm_proj(
    const unsigned short* __restrict__ A, const unsigned short* __restrict__ Bt,
    float* __restrict__ Cout, const float* __restrict__ bias, int M, int N, int K) {
  __shared__ unsigned short As[128][64];
  __shared__ unsigned short Bs[64][64];
  int tid = threadIdx.x;
  int w = tid >> 6, lane = tid & 63, quad = lane >> 4, l16 = lane & 15;
  int rowB = blockIdx.y * 128, colB = blockIdx.x * 64;
  int srcRow = lane >> 3;
  int srcCol = (((lane & 7) ^ (srcRow & 7)) << 3);

  floatx4 acc[2][4];
  floatx4 zero4 = {0.f, 0.f, 0.f, 0.f};
#pragma unroll
  for (int mi = 0; mi < 2; ++mi)
#pragma unroll
    for (int ni = 0; ni < 4; ++ni) acc[mi][ni] = zero4;

  for (int kt = 0; kt < K; kt += 64) {
    __syncthreads();
#pragma unroll
    for (int i = 0; i < 4; ++i) {
      int r0 = w * 32 + i * 8;
      async_cp16(&A[(size_t)(rowB + r0 + srcRow) * K + kt + srcCol], &As[r0][0]);
    }
#pragma unroll
    for (int i = 0; i < 2; ++i) {
      int r0 = w * 16 + i * 8;
      async_cp16(&Bt[(size_t)(colB + r0 + srcRow) * K + kt + srcCol], &Bs[r0][0]);
    }
    __syncthreads();
#pragma unroll
    for (int kh = 0; kh < 2; ++kh) {
      short8 af[2], bf_[4];
#pragma unroll
      for (int mi = 0; mi < 2; ++mi)
        af[mi] = ld8(&As[w * 32 + mi * 16 + l16][((kh * 4 + quad) ^ (l16 & 7)) << 3]);
#pragma unroll
      for (int ni = 0; ni < 4; ++ni)
        bf_[ni] = ld8(&Bs[ni * 16 + l16][((kh * 4 + quad) ^ (l16 & 7)) << 3]);
#pragma unroll
      for (int mi = 0; mi < 2; ++mi)
#pragma unroll
        for (int ni = 0; ni < 4; ++ni)
          acc[mi][ni] = MFMA16(af[mi], bf_[ni], acc[mi][ni]);
    }
  }

#pragma unroll
  for (int mi = 0; mi < 2; ++mi) {
    int row = rowB + w * 32 + mi * 16 + quad * 4;
#pragma unroll
    for (int ni = 0; ni < 4; ++ni) {
      int col = colB + ni * 16 + l16;
      float bv = bias[col];
#pragma unroll
      for (int r = 0; r < 4; ++r)
        Cout[(size_t)(row + r) * N + col] = acc[mi][ni][r] + bv;
    }
  }
}

// ---------------- flash attention, causal, fixed-offset softmax ----------------
// R19: single-stream q-split occupancy doubling (no cross-block combine).
// Each block owns ONE 64-row q-tile j (full causal key range 0..(j+1)*64), so
// o/l finish in-block: no partials, no fences, no counters. Grid 512 -> 1024,
// LDS 28.2 KB -> 4 blocks/CU (16 waves, was 8). NO min-waves launch_bounds
// hint: R18's (256,4) clamped VGPR to 64 and spilled accumulators to scratch
// (WRITE_SIZE 8->144 MB, MfmaUtil 2.7%). Register state here is ~half of R17's
// two-stream version, so the default allocator stays well under 128.
// Work per block is proportional to j+1; balance via decode: XCD-affine
// (idx&7 = XCD), round r = bh = xcd*4+r, q-tile j = perm_r(p) with perms
// {p, 31-p, (p+16)&31, 31-((p+16)&31)} -> per-CU work sum is a constant 66
// key-tile units under round-robin dispatch (heuristic only, not correctness).
// Rest frozen at R16: S^T = K*Q^T, fixed-offset softmax p = exp2(s*c-16),
// l via ones-MFMA, RNE b64 P-pack, Pt stride 76, reg-prefetch of next K/V tile.
__global__ __launch_bounds__(256) void k_attn(
    const unsigned short* __restrict__ qk, const unsigned short* __restrict__ vT,
    unsigned short* __restrict__ attn_out) {
  const int T = 2048, LD = 2048;
  __shared__ unsigned short Kt[64][72];    // [key][d]   64-key stage
  __shared__ unsigned short Vt[64][72];    // [d][key]
  __shared__ unsigned short Pt[4][16][76]; // per-wave P [q][key64]

  // decode: idx&7 = XCD slot; per-XCD stream s = (round r, position p)
  int idx = blockIdx.x;
  int s = idx >> 3;
  int r = s >> 5, p = s & 31;
  int pp = (r & 2) ? ((p + 16) & 31) : p;
  int j = (r & 1) ? (31 - pp) : pp;        // q-tile 0..31
  int bh = (idx & 7) * 4 + r;              // 0..31
  int b = bh >> 4, h = bh & 15;
  int tid = threadIdx.x, w = tid >> 6, lane = tid & 63;
  int quad = lane >> 4, l16 = lane & 15;

  const unsigned short* Qp = qk + (size_t)b * T * LD + h * 64;
  const unsigned short* Kp = Qp + 1024;
  const unsigned short* Vp = vT + (size_t)bh * 64 * T;

  int q0 = j * 64;
  int nt = j + 1;  // 64-key tiles in this block's causal range

  short8 aq[2];
  {
    const unsigned short* qrow = Qp + (size_t)(q0 + w * 16 + l16) * LD + quad * 8;
    aq[0] = ld8(qrow);
    aq[1] = ld8(qrow + 32);
  }

  short8 ones8;
  {
    unsigned short o = 0x3F80;  // bf16 1.0
#pragma unroll
    for (int i = 0; i < 8; ++i) ones8[i] = (short)o;
  }

  const float cscale = 0.125f * 1.44269504f;
  floatx4 o_acc[4], l_acc;
  floatx4 zero4 = {0.f, 0.f, 0.f, 0.f};
  l_acc = zero4;
#pragma unroll
  for (int nd = 0; nd < 4; ++nd) o_acc[nd] = zero4;

  // staging coords: K 64x64 (32 rows/pass x2), V^T 64x64 (32 rows/pass x2)
  int skR = tid >> 3, skC = (tid & 7) << 3;

  short8 kreg[2], vreg[2];
#pragma unroll
  for (int i = 0; i < 2; ++i) {
    kreg[i] = ld8(&Kp[(size_t)(skR + i * 32) * LD + skC]);
    vreg[i] = ld8(&Vp[(size_t)(skR + i * 32) * T + skC]);
  }

  for (int half = 0; half < nt; ++half) {
    __syncthreads();
#pragma unroll
    for (int i = 0; i < 2; ++i) {
      *reinterpret_cast<short8*>(&Kt[skR + i * 32][skC]) = kreg[i];
      *reinterpret_cast<short8*>(&Vt[skR + i * 32][skC]) = vreg[i];
    }
    __syncthreads();

    if (half + 1 < nt) {  // prefetch next 64-key tile during compute
      int key0n = (half + 1) * 64;
#pragma unroll
      for (int i = 0; i < 2; ++i) {
        kreg[i] = ld8(&Kp[(size_t)(key0n + skR + i * 32) * LD + skC]);
        vreg[i] = ld8(&Vp[(size_t)(skR + i * 32) * T + key0n + skC]);
      }
    }

    int key0 = half * 64;

    // S^T = K Q^T; C-layout: col=q=l16, row=key=kt4*16+quad*4+reg
    floatx4 st[4];
#pragma unroll
    for (int kt4 = 0; kt4 < 4; ++kt4) {
      short8 ak0 = ld8(&Kt[kt4 * 16 + l16][quad * 8]);
      short8 ak1 = ld8(&Kt[kt4 * 16 + l16][32 + quad * 8]);
      st[kt4] = MFMA16(ak0, aq[0], zero4);
      st[kt4] = MFMA16(ak1, aq[1], st[kt4]);
    }

    if (half == j) {  // wave-uniform: mask only on diagonal tile
      int qlane = q0 + w * 16 + l16;
#pragma unroll
      for (int kt4 = 0; kt4 < 4; ++kt4)
#pragma unroll
        for (int rr = 0; rr < 4; ++rr)
          if (key0 + kt4 * 16 + quad * 4 + rr > qlane) st[kt4][rr] = -1e30f;
    }

#pragma unroll
    for (int kt4 = 0; kt4 < 4; ++kt4) {
      unsigned u[4];
#pragma unroll
      for (int rr = 0; rr < 4; ++rr) {
        float pe = __builtin_amdgcn_exp2f(fmaf(st[kt4][rr], cscale, -16.f));
        u[rr] = __float_as_uint(pe) + 0x8000u;
      }
      unsigned lo = __builtin_amdgcn_perm(u[1], u[0], 0x07060302u);
      unsigned hi = __builtin_amdgcn_perm(u[3], u[2], 0x07060302u);
      unsigned long long pv = ((unsigned long long)hi << 32) | lo;
      *reinterpret_cast<unsigned long long*>(
          &Pt[w][l16][kt4 * 16 + quad * 4]) = pv;
    }

    short8 pa0 = ld8(&Pt[w][l16][quad * 8]);
    short8 pa1 = ld8(&Pt[w][l16][32 + quad * 8]);
#pragma unroll
    for (int nd = 0; nd < 4; ++nd) {
      short8 bv0 = ld8(&Vt[nd * 16 + l16][quad * 8]);
      short8 bv1 = ld8(&Vt[nd * 16 + l16][32 + quad * 8]);
      o_acc[nd] = MFMA16(pa0, bv0, o_acc[nd]);
      o_acc[nd] = MFMA16(pa1, bv1, o_acc[nd]);
    }
    l_acc = MFMA16(pa0, ones8, l_acc);
    l_acc = MFMA16(pa1, ones8, l_acc);
  }

  // epilogue: attn_out [B*T][1024] bf16 (C-layout: row=quad*4+r, col=l16)
#pragma unroll
  for (int nd = 0; nd < 4; ++nd)
#pragma unroll
    for (int rr = 0; rr < 4; ++rr) {
      int q = q0 + w * 16 + quad * 4 + rr;
      int d = nd * 16 + l16;
      attn_out[(size_t)(b * T + q) * 1024 + h * 64 + d] =
          f2bf(o_acc[nd][rr] / l_acc[rr]);
    }
}

extern "C" void kernel_launch(void* const* d_in, const int* in_sizes, int n_in,
                              void* d_out, int out_size, void* d_ws, size_t ws_size,
                              hipStream_t stream) {
  const float* x = (const float*)d_in[0];       // [2,2048,1024]
  const float* w_qkv = (const float*)d_in[1];   // [1024,3072]
  const float* w_proj = (const float*)d_in[2];  // [1024,1024]
  const float* b_proj = (const float*)d_in[3];  // [1024]
  float* out = (float*)d_out;                   // [2,2048,1024] fp32

  char* ws = (char*)d_ws;
  unsigned short* xb     = (unsigned short*)(ws);                      // 8 MB
  unsigned short* wqkvT  = (unsigned short*)(ws + (size_t)(8  << 20)); // 6 MB
  unsigned short* wprojT = (unsigned short*)(ws + (size_t)(14 << 20)); // 2 MB
  unsigned short* qkb    = (unsigned short*)(ws + (size_t)(16 << 20)); // 16 MB (Q|K, LD 2048)
  unsigned short* attnb  = (unsigned short*)(ws + (size_t)(32 << 20)); // 8 MB
  unsigned short* vTb    = (unsigned short*)(ws + (size_t)(40 << 20)); // 8 MB

  k_prep<<<5120, 256, 0, stream>>>(x, xb, w_qkv, wqkvT, w_proj, wprojT);
  k_gemm_qkv<<<dim3(3072 / 128, 4096 / 128), 256, 0, stream>>>(
      xb, wqkvT, qkb, vTb, 1024);
  k_attn<<<1024, 256, 0, stream>>>(qkb, vTb, attnb);
  k_gemm_proj<<<dim3(1024 / 64, 4096 / 128), 256, 0, stream>>>(
      attnb, wprojT, out, b_proj, 4096, 1024, 1024);
}